// Round 3
// baseline (572.094 us; speedup 1.0000x reference)
//
#include <hip/hip_runtime.h>

// out[b,s,j] = sum_k x[b,s,k] * w_concat[inv_perm[j], k] + bias[j]
// Folded: pack permuted bf16 weights Wp (exact: |q|<=128), per-row scale,
// x -> bf16 once, ONE bf16 MFMA GEMM with acc*scale+bias epilogue.
// GEMM: 256x256 tile, BK=64, 8 waves, 8-phase counted-vmcnt schedule (T3+T4),
// XOR-swizzled LDS (T2) via pre-swizzled global_load_lds source, setprio (T5),
// bijective XCD-aware block remap (T1) for L2-local staging.

#define M_TOK 16384
#define N_O   4096
#define K_IN  4096
#define N8F   2048
#define NT    (K_IN / 64)   // 64 K-tiles of BK=64

typedef __attribute__((ext_vector_type(8))) short bf16x8;
typedef __attribute__((ext_vector_type(4))) float f32x4;

__device__ __forceinline__ unsigned short f2bf(float f) {
  union { float f; unsigned u; } v; v.f = f;
  unsigned r = v.u + 0x7fffu + ((v.u >> 16) & 1u);   // RTNE
  return (unsigned short)(r >> 16);
}

__device__ __forceinline__ void gl_lds16(const void* g, void* l) {
  __builtin_amdgcn_global_load_lds(
      (const __attribute__((address_space(1))) unsigned int*)g,
      (__attribute__((address_space(3))) unsigned int*)l, 16, 0, 0);
}

// ------------- fused prep: blocks [0,N_O) pack weights; rest convert x -------------
__global__ void prep_kernel(const int4* __restrict__ q8, const float* __restrict__ s8,
                            const int4* __restrict__ q4, const float* __restrict__ s4,
                            const int* __restrict__ inv_perm,
                            unsigned short* __restrict__ Wp, float* __restrict__ scale_out,
                            const float4* __restrict__ x, uint4* __restrict__ xb) {
  if (blockIdx.x < N_O) {
    const int j = blockIdx.x;
    const int c = inv_perm[j];
    const int4* src;
    float s;
    if (c < N8F) { src = q8 + (size_t)c * (K_IN / 4);         s = s8[c]; }
    else         { src = q4 + (size_t)(c - N8F) * (K_IN / 4); s = s4[c - N8F]; }
    if (threadIdx.x == 0) scale_out[j] = s;
    ushort4* dst = (ushort4*)(Wp + (size_t)j * K_IN);
    for (int k4 = threadIdx.x; k4 < K_IN / 4; k4 += blockDim.x) {
      int4 v = src[k4];
      ushort4 o;
      o.x = f2bf((float)v.x);
      o.y = f2bf((float)v.y);
      o.z = f2bf((float)v.z);
      o.w = f2bf((float)v.w);
      dst[k4] = o;
    }
  } else {
    const int n8 = M_TOK * K_IN / 8;
    const int nb = 2048;                      // cvt blocks
    int idx = (blockIdx.x - N_O) * blockDim.x + threadIdx.x;
    const int stride = nb * blockDim.x;
    for (; idx < n8; idx += stride) {
      float4 a = x[2 * idx], b = x[2 * idx + 1];
      uint4 o;
      o.x = f2bf(a.x) | ((unsigned)f2bf(a.y) << 16);
      o.y = f2bf(a.z) | ((unsigned)f2bf(a.w) << 16);
      o.z = f2bf(b.x) | ((unsigned)f2bf(b.y) << 16);
      o.w = f2bf(b.z) | ((unsigned)f2bf(b.w) << 16);
      xb[idx] = o;
    }
  }
}

// ================= 256x256 8-phase GEMM =================
// LDS map (bytes): buf*65536 + { A: half*16384 | B: 32768 + half*16384 }
// half = 128 rows x 64 bf16 (128B rows), swizzle: phys_colbyte = log ^ ((row&7)<<4)
__global__ __launch_bounds__(512, 2)
void gemm8p(const unsigned short* __restrict__ xb, const unsigned short* __restrict__ Wp,
            const float* __restrict__ scale, const float* __restrict__ bias,
            float* __restrict__ out) {
  __shared__ __align__(16) char sm[131072];
  const int t = threadIdx.x;
  const int w = t >> 6, l = t & 63;
  const int wr = w >> 2, wc = w & 3;          // 2M x 4N waves

  // --- bijective XCD-aware remap: 1024 blocks, 8 chunks (one per XCD) along bm.
  // Within a chunk the 32 concurrently-resident blocks form 8bm x 4bn, so each
  // XCD's per-K-tile staging working set is 12 half-tile streams (~384 KB in L2).
  const int wg = blockIdx.x;
  const int xcd = wg & 7, local_ = wg >> 3;
  const int sub = local_ >> 5, pos = local_ & 31;
  const int bm = (xcd << 3) | (pos >> 2);     // [0,64)
  const int bn = (sub << 2) | (pos & 3);      // [0,16)
  const int row0 = bm * 256, col0 = bn * 256;

  // --- staging: per-lane pre-swizzled global source (rule #21) ---
  const int srow = l >> 3;                              // row within 8-row group
  const int schunk = ((l & 7) ^ srow) * 16;             // inverse-swizzled 16B chunk
  const char* aG = (const char*)xb + (size_t)(row0 + w * 16 + srow) * (K_IN * 2) + schunk;
  const char* bG = (const char*)Wp + (size_t)(col0 + w * 16 + srow) * (K_IN * 2) + schunk;
  char* aL0 = sm + w * 2048;                            // + buf*65536 + h*16384
  char* bL0 = sm + 32768 + w * 2048;

  auto stageA = [&](int buf, int kt, int h) {
    const char* g = aG + (size_t)h * (128 * K_IN * 2) + (size_t)kt * 128;
    char* p = aL0 + buf * 65536 + h * 16384;
    gl_lds16(g, p);
    gl_lds16(g + 8 * (K_IN * 2), p + 1024);
  };
  auto stageB = [&](int buf, int kt, int h) {
    const char* g = bG + (size_t)h * (128 * K_IN * 2) + (size_t)kt * 128;
    char* p = bL0 + buf * 65536 + h * 16384;
    gl_lds16(g, p);
    gl_lds16(g + 8 * (K_IN * 2), p + 1024);
  };

  // --- fragment-read per-lane offsets (swizzled) ---
  const int lrow128 = (l & 15) * 128;
  const int cb0 = (((l >> 4) << 4) ^ ((l & 7) << 4));   // kk=0 colbyte; kk=1: ^64
  const int aWoff = wr * 16384 + lrow128;
  const int bWoff = 32768 + (wc >> 1) * 16384 + (wc & 1) * 8192 + lrow128;

  f32x4 acc[8][4];
#pragma unroll
  for (int m = 0; m < 8; ++m)
#pragma unroll
    for (int n = 0; n < 4; ++n) acc[m][n] = (f32x4){0.f, 0.f, 0.f, 0.f};

  // --- prologue: tile0 fully + tile1 {B0,B1,A0}; wait tile0 (vmcnt 14->6) ---
  stageB(0, 0, 0); stageB(0, 0, 1); stageA(0, 0, 0); stageA(0, 0, 1);
  stageB(1, 1, 0); stageB(1, 1, 1); stageA(1, 1, 0);
  asm volatile("s_waitcnt vmcnt(6)" ::: "memory");
  __builtin_amdgcn_s_barrier();

  bf16x8 bfr[4][2], afr[2][2], afr2[2][2];

  for (int kt = 0; kt < NT; ++kt) {
    const int cur = kt & 1;
    const char* smA = sm + cur * 65536 + aWoff;
    const char* smB = sm + cur * 65536 + bWoff;

    // ---- phase 1: ds_read all B (8) + A mg0 (4); stage A1(kt+1) -> buf^1
#pragma unroll
    for (int n = 0; n < 4; ++n) {
      bfr[n][0] = *(const bf16x8*)(smB + n * 2048 + cb0);
      bfr[n][1] = *(const bf16x8*)(smB + n * 2048 + (cb0 ^ 64));
    }
#pragma unroll
    for (int m = 0; m < 2; ++m) {
      afr[m][0] = *(const bf16x8*)(smA + m * 2048 + cb0);
      afr[m][1] = *(const bf16x8*)(smA + m * 2048 + (cb0 ^ 64));
    }
    if (kt + 1 < NT) stageA(cur ^ 1, kt + 1, 1);
    __builtin_amdgcn_s_barrier();
    asm volatile("s_waitcnt lgkmcnt(0)" ::: "memory");
    __builtin_amdgcn_s_setprio(1);
#pragma unroll
    for (int m = 0; m < 2; ++m)
#pragma unroll
      for (int n = 0; n < 4; ++n)
#pragma unroll
        for (int kk = 0; kk < 2; ++kk)
          acc[m][n] = __builtin_amdgcn_mfma_f32_16x16x32_bf16(afr[m][kk], bfr[n][kk],
                                                              acc[m][n], 0, 0, 0);
    __builtin_amdgcn_s_setprio(0);
    __builtin_amdgcn_s_barrier();

    // ---- phase 2: ds_read A mg1 (4); stage B0(kt+2) -> buf cur (region free since p1)
#pragma unroll
    for (int m = 0; m < 2; ++m) {
      afr[m][0] = *(const bf16x8*)(smA + (2 + m) * 2048 + cb0);
      afr[m][1] = *(const bf16x8*)(smA + (2 + m) * 2048 + (cb0 ^ 64));
    }
    if (kt + 2 < NT) stageB(cur, kt + 2, 0);
    __builtin_amdgcn_s_barrier();
    asm volatile("s_waitcnt lgkmcnt(0)" ::: "memory");
    __builtin_amdgcn_s_setprio(1);
#pragma unroll
    for (int m = 0; m < 2; ++m)
#pragma unroll
      for (int n = 0; n < 4; ++n)
#pragma unroll
        for (int kk = 0; kk < 2; ++kk)
          acc[2 + m][n] = __builtin_amdgcn_mfma_f32_16x16x32_bf16(afr[m][kk], bfr[n][kk],
                                                                  acc[2 + m][n], 0, 0, 0);
    __builtin_amdgcn_s_setprio(0);
    __builtin_amdgcn_s_barrier();

    // ---- phase 3: ds_read A mg2 (4) + A mg3 prefetch (4); stage B1(kt+2)
#pragma unroll
    for (int m = 0; m < 2; ++m) {
      afr[m][0]  = *(const bf16x8*)(smA + (4 + m) * 2048 + cb0);
      afr[m][1]  = *(const bf16x8*)(smA + (4 + m) * 2048 + (cb0 ^ 64));
      afr2[m][0] = *(const bf16x8*)(smA + (6 + m) * 2048 + cb0);
      afr2[m][1] = *(const bf16x8*)(smA + (6 + m) * 2048 + (cb0 ^ 64));
    }
    if (kt + 2 < NT) stageB(cur, kt + 2, 1);
    __builtin_amdgcn_s_barrier();
    asm volatile("s_waitcnt lgkmcnt(0)" ::: "memory");   // full drain: A regions reused in p4
    __builtin_amdgcn_s_setprio(1);
#pragma unroll
    for (int m = 0; m < 2; ++m)
#pragma unroll
      for (int n = 0; n < 4; ++n)
#pragma unroll
        for (int kk = 0; kk < 2; ++kk)
          acc[4 + m][n] = __builtin_amdgcn_mfma_f32_16x16x32_bf16(afr[m][kk], bfr[n][kk],
                                                                  acc[4 + m][n], 0, 0, 0);
    __builtin_amdgcn_s_setprio(0);
    __builtin_amdgcn_s_barrier();

    // ---- phase 4: stage A0(kt+2); counted vmcnt (tile kt+1 landed, 3 halves in flight)
    if (kt + 2 < NT) {
      stageA(cur, kt + 2, 0);
      asm volatile("s_waitcnt vmcnt(6)" ::: "memory");
    } else {
      asm volatile("s_waitcnt vmcnt(0)" ::: "memory");
    }
    __builtin_amdgcn_s_barrier();
    __builtin_amdgcn_s_setprio(1);
#pragma unroll
    for (int m = 0; m < 2; ++m)
#pragma unroll
      for (int n = 0; n < 4; ++n)
#pragma unroll
        for (int kk = 0; kk < 2; ++kk)
          acc[6 + m][n] = __builtin_amdgcn_mfma_f32_16x16x32_bf16(afr2[m][kk], bfr[n][kk],
                                                                  acc[6 + m][n], 0, 0, 0);
    __builtin_amdgcn_s_setprio(0);
    __builtin_amdgcn_s_barrier();
  }

  // ---- epilogue: C/D layout col=lane&15, row=(lane>>4)*4+i ; out = acc*scale+bias
  const int orow0 = row0 + wr * 128 + ((l >> 4) << 2);
  const int ocol0 = col0 + wc * 64 + (l & 15);
#pragma unroll
  for (int n = 0; n < 4; ++n) {
    const int col = ocol0 + n * 16;
    const float sc = scale[col];
    const float bi = bias[col];
#pragma unroll
    for (int m = 0; m < 8; ++m) {
      const int r = orow0 + m * 16;
#pragma unroll
      for (int i = 0; i < 4; ++i)
        out[(size_t)(r + i) * N_O + col] = acc[m][n][i] * sc + bi;
    }
  }
}

// ================= fallback (ws too small for xb): 128^2, f32 A staging ======
__global__ __launch_bounds__(256, 2)
void gemm_fb(const float* __restrict__ xf, const unsigned short* __restrict__ Wp,
             const float* __restrict__ scale, const float* __restrict__ bias,
             float* __restrict__ out) {
  __shared__ __align__(16) unsigned short As[2][128][32];
  __shared__ __align__(16) unsigned short Bs[2][128][32];
  const int t = threadIdx.x;
  const int w = t >> 6, l = t & 63;
  const int bn = blockIdx.x & 31;
  const int bm = blockIdx.x >> 5;
  const int row0 = bm * 128, col0 = bn * 128;
  const int srow = t >> 2, scol = (t & 3) * 8;
  const unsigned short* Bg = Wp + (size_t)(col0 + srow) * K_IN + scol;
  const int farow = t >> 1, fac0 = (t & 1) * 16;
  const float* Agf = xf + (size_t)(row0 + farow) * K_IN + fac0;

  auto stage = [&](int buf, int kt) {
    const unsigned short* bg = Bg + (size_t)kt * 32;
    char* bb = (char*)Bs + buf * 8192 + w * 1024;
    gl_lds16(bg, bb);
    gl_lds16(bg + (size_t)64 * K_IN, bb + 4096);
    const float* af = Agf + (size_t)kt * 32;
    unsigned int o[8];
#pragma unroll
    for (int i = 0; i < 4; ++i) {
      float4 v = *(const float4*)(af + i * 4);
      o[i * 2 + 0] = f2bf(v.x) | ((unsigned)f2bf(v.y) << 16);
      o[i * 2 + 1] = f2bf(v.z) | ((unsigned)f2bf(v.w) << 16);
    }
    uint4* d = (uint4*)((char*)As + buf * 8192 + farow * 64 + fac0 * 2);
    d[0] = make_uint4(o[0], o[1], o[2], o[3]);
    d[1] = make_uint4(o[4], o[5], o[6], o[7]);
  };

  const int wr = w >> 1, wc = w & 1;
  const int lr = l & 15, lk = (l >> 4) * 8;
  f32x4 acc[4][4];
#pragma unroll
  for (int i = 0; i < 4; ++i)
#pragma unroll
    for (int j = 0; j < 4; ++j) acc[i][j] = (f32x4){0.f, 0.f, 0.f, 0.f};

  stage(0, 0);
  int cur = 0;
  for (int kt = 0; kt < K_IN / 32; ++kt) {
    __syncthreads();
    if (kt + 1 < K_IN / 32) stage(cur ^ 1, kt + 1);
    bf16x8 av[4], bv[4];
#pragma unroll
    for (int fm = 0; fm < 4; ++fm)
      av[fm] = *(const bf16x8*)((const char*)As + cur * 8192 + (wr * 64 + fm * 16 + lr) * 64 + lk * 2);
#pragma unroll
    for (int fn = 0; fn < 4; ++fn)
      bv[fn] = *(const bf16x8*)((const char*)Bs + cur * 8192 + (wc * 64 + fn * 16 + lr) * 64 + lk * 2);
#pragma unroll
    for (int fm = 0; fm < 4; ++fm)
#pragma unroll
      for (int fn = 0; fn < 4; ++fn)
        acc[fm][fn] = __builtin_amdgcn_mfma_f32_16x16x32_bf16(av[fm], bv[fn], acc[fm][fn], 0, 0, 0);
    cur ^= 1;
  }
  const int orow = row0 + wr * 64 + (l >> 4) * 4;
  const int ocol0 = col0 + wc * 64 + lr;
#pragma unroll
  for (int fn = 0; fn < 4; ++fn) {
    const int col = ocol0 + fn * 16;
    const float sc = scale[col];
    const float bi = bias[col];
#pragma unroll
    for (int fm = 0; fm < 4; ++fm) {
      const int r = orow + fm * 16;
#pragma unroll
      for (int i = 0; i < 4; ++i)
        out[(size_t)(r + i) * N_O + col] = acc[fm][fn][i] * sc + bi;
    }
  }
}

extern "C" void kernel_launch(void* const* d_in, const int* in_sizes, int n_in,
                              void* d_out, int out_size, void* d_ws, size_t ws_size,
                              hipStream_t stream) {
  const float* x    = (const float*)d_in[0];
  const int*   q8   = (const int*)d_in[1];
  const float* s8   = (const float*)d_in[2];
  const int*   q4   = (const int*)d_in[3];
  const float* s4   = (const float*)d_in[4];
  const int*   inv  = (const int*)d_in[5];
  const float* bias = (const float*)d_in[6];
  float* out = (float*)d_out;

  char* ws = (char*)d_ws;
  unsigned short* Wp = (unsigned short*)ws;                         // 32 MiB
  const size_t wp_bytes = (size_t)N_O * K_IN * 2;
  float* scale = (float*)(ws + wp_bytes);                           // 16 KiB
  unsigned short* xb = (unsigned short*)(ws + wp_bytes + 65536);    // 128 MiB
  const size_t need_full = wp_bytes + 65536 + (size_t)M_TOK * K_IN * 2;

  if (ws_size >= need_full) {
    prep_kernel<<<N_O + 2048, 256, 0, stream>>>((const int4*)q8, s8, (const int4*)q4, s4,
                                                inv, Wp, scale, (const float4*)x, (uint4*)xb);
    gemm8p<<<(M_TOK / 256) * (N_O / 256), 512, 0, stream>>>(xb, Wp, scale, bias, out);
  } else {
    prep_kernel<<<N_O, 256, 0, stream>>>((const int4*)q8, s8, (const int4*)q4, s4,
                                         inv, Wp, scale, nullptr, nullptr);
    gemm_fb<<<(M_TOK / 128) * (N_O / 128), 256, 0, stream>>>(x, Wp, scale, bias, out);
  }
}

// Round 4
// 388.912 us; speedup vs baseline: 1.4710x; 1.4710x over previous
//
#include <hip/hip_runtime.h>

// out[b,s,j] = sum_k x[b,s,k] * w_concat[inv_perm[j], k] + bias[j]
// Round-3 strategy: INT8 path. Weights are integers (q8 in [-128,127], q4 in
// [-8,7]) -> exact i8. x quantized per-token: sx[t]=absmax/127, xq=round(x/sx)
// clamped to +-127. One i8 MFMA GEMM (mfma_i32_16x16x64_i8, 2x bf16 rate),
// i32 accumulation (exact), epilogue out = acc * sx[row]*scale[col] + bias[col].
// GEMM: 256x256 tile, BK=64, 8 waves, 2-phase/K-tile counted-vmcnt schedule,
// XOR-swizzled LDS (chunk ^= (row>>1)&3) via pre-swizzled global source.

#define M_TOK 16384
#define N_O   4096
#define K_IN  4096
#define N8F   2048
#define NT    (K_IN / 64)   // 64 K-tiles of BK=64 (64 bytes/row in i8)

typedef __attribute__((ext_vector_type(4))) int   i32x4;
typedef __attribute__((ext_vector_type(4))) float f32x4;

__device__ __forceinline__ void gl_lds16(const void* g, void* l) {
  __builtin_amdgcn_global_load_lds(
      (const __attribute__((address_space(1))) unsigned int*)g,
      (__attribute__((address_space(3))) unsigned int*)l, 16, 0, 0);
}

__device__ __forceinline__ int clampq(float f) {
  int q = (int)rintf(f);
  return q > 127 ? 127 : (q < -127 ? -127 : q);
}

// ---- fused prep: blocks [0,N_O) pack weights to i8; blocks [N_O, N_O+M_TOK)
// ---- quantize one token each (absmax -> sx, xq).
__global__ void prep_kernel(const float* __restrict__ x,
                            const int4* __restrict__ q8, const float* __restrict__ s8,
                            const int4* __restrict__ q4, const float* __restrict__ s4,
                            const int* __restrict__ inv,
                            char* __restrict__ Wq, float* __restrict__ scale,
                            float* __restrict__ sx, char* __restrict__ xq) {
  __shared__ float red[4];
  const int t = threadIdx.x;
  if (blockIdx.x < N_O) {
    const int j = blockIdx.x;
    const int c = inv[j];
    const int4* src; float s;
    if (c < N8F) { src = q8 + (size_t)c * (K_IN / 4);         s = s8[c]; }
    else         { src = q4 + (size_t)(c - N8F) * (K_IN / 4); s = s4[c - N8F]; }
    if (t == 0) scale[j] = s;
    unsigned dw[4];
#pragma unroll
    for (int i = 0; i < 4; ++i) {
      int4 v = src[t * 4 + i];
      dw[i] = (v.x & 255) | ((v.y & 255) << 8) | ((v.z & 255) << 16)
            | ((unsigned)(v.w & 255) << 24);
    }
    *(uint4*)(Wq + (size_t)j * K_IN + t * 16) = make_uint4(dw[0], dw[1], dw[2], dw[3]);
  } else {
    const int T = blockIdx.x - N_O;
    const float4* xr = (const float4*)(x + (size_t)T * K_IN);
    float4 v[4];
    float m = 0.f;
#pragma unroll
    for (int i = 0; i < 4; ++i) {
      v[i] = xr[t * 4 + i];
      m = fmaxf(m, fmaxf(fmaxf(fabsf(v[i].x), fabsf(v[i].y)),
                         fmaxf(fabsf(v[i].z), fabsf(v[i].w))));
    }
#pragma unroll
    for (int o = 32; o; o >>= 1) m = fmaxf(m, __shfl_xor(m, o));
    if ((t & 63) == 0) red[t >> 6] = m;
    __syncthreads();
    m = fmaxf(fmaxf(red[0], red[1]), fmaxf(red[2], red[3]));
    const float rq = m > 0.f ? 127.f / m : 0.f;
    if (t == 0) sx[T] = m * (1.f / 127.f);
    unsigned dw[4];
#pragma unroll
    for (int i = 0; i < 4; ++i) {
      int a0 = clampq(v[i].x * rq), a1 = clampq(v[i].y * rq);
      int a2 = clampq(v[i].z * rq), a3 = clampq(v[i].w * rq);
      dw[i] = (a0 & 255) | ((a1 & 255) << 8) | ((a2 & 255) << 16)
            | ((unsigned)(a3 & 255) << 24);
    }
    *(uint4*)(xq + (size_t)T * K_IN + t * 16) = make_uint4(dw[0], dw[1], dw[2], dw[3]);
  }
}

// ================= 256x256 i8 GEMM, BK=64, 2-phase counted-vmcnt =================
// LDS (64 KiB): buf*32768 + { A: h*8192 | B: 16384 + h*8192 }
// half = 128 rows x 64 i8 (64B rows); swizzle: phys_chunk = chunk ^ ((row>>1)&3)
__global__ __launch_bounds__(512, 2)
void gemm_i8(const char* __restrict__ xq, const char* __restrict__ Wq,
             const float* __restrict__ sx, const float* __restrict__ scale,
             const float* __restrict__ bias, float* __restrict__ out) {
  __shared__ __align__(16) char sm[65536];
  const int t = threadIdx.x;
  const int w = t >> 6, l = t & 63;
  const int wr = w >> 2, wc = w & 3;            // 2M x 4N waves, 128x64 each
  const int bm = blockIdx.x >> 4, bn = blockIdx.x & 15;   // linear (no XCD remap)
  const int row0 = bm * 256, col0 = bn * 256;

  // staging: wave w covers rows w*16..w*16+15 of each 128-row half; lane l ->
  // row-in-slice l>>2, phys chunk l&3; global source chunk inverse-swizzled.
  const int srow = l >> 2;
  const int schunk = ((l & 3) ^ ((l >> 3) & 3)) * 16;
  const char* aG = xq + (size_t)(row0 + w * 16 + srow) * K_IN + schunk;
  const char* bG = Wq + (size_t)(col0 + w * 16 + srow) * K_IN + schunk;
  char* aL0 = sm + w * 1024;
  char* bL0 = sm + 16384 + w * 1024;

  auto stageA = [&](int buf, int kt, int h) {
    gl_lds16(aG + (size_t)h * (128 * K_IN) + kt * 64, aL0 + buf * 32768 + h * 8192);
  };
  auto stageB = [&](int buf, int kt, int h) {
    gl_lds16(bG + (size_t)h * (128 * K_IN) + kt * 64, bL0 + buf * 32768 + h * 8192);
  };

  // fragment read: row_local = frag*16 + (l&15), k-chunk = l>>4, swizzled
  const int fRoff = (l & 15) * 64 + ((((l >> 4) ^ ((l >> 1) & 3))) << 4);
  const int aOff = wr * 8192 + fRoff;
  const int bOff = 16384 + (wc >> 1) * 8192 + (wc & 1) * 4096 + fRoff;

  i32x4 acc[8][4];
#pragma unroll
  for (int m = 0; m < 8; ++m)
#pragma unroll
    for (int n = 0; n < 4; ++n) acc[m][n] = (i32x4){0, 0, 0, 0};

  // prologue: tile0 {A0,A1,B0,B1} + tile1 {B0,B1}; drain tile0 -> vmcnt(2)
  stageA(0, 0, 0); stageA(0, 0, 1); stageB(0, 0, 0); stageB(0, 0, 1);
  stageB(1, 1, 0); stageB(1, 1, 1);
  asm volatile("s_waitcnt vmcnt(2)" ::: "memory");
  __builtin_amdgcn_s_barrier();

  i32x4 afr[4], bfr[4];

  for (int kt = 0; kt < NT; ++kt) {
    const int cur = kt & 1;
    const char* smA = sm + cur * 32768 + aOff;
    const char* smB = sm + cur * 32768 + bOff;

    // ---- phase 1: read all B (4) + A m0-3 (4); stage A(kt+1) -> buf^1
#pragma unroll
    for (int n = 0; n < 4; ++n) bfr[n] = *(const i32x4*)(smB + n * 1024);
#pragma unroll
    for (int m = 0; m < 4; ++m) afr[m] = *(const i32x4*)(smA + m * 1024);
    if (kt + 1 < NT) { stageA(cur ^ 1, kt + 1, 0); stageA(cur ^ 1, kt + 1, 1); }
    __builtin_amdgcn_s_barrier();
    asm volatile("s_waitcnt lgkmcnt(0)" ::: "memory");
    __builtin_amdgcn_s_setprio(1);
#pragma unroll
    for (int m = 0; m < 4; ++m)
#pragma unroll
      for (int n = 0; n < 4; ++n)
        acc[m][n] = __builtin_amdgcn_mfma_i32_16x16x64_i8(afr[m], bfr[n],
                                                          acc[m][n], 0, 0, 0);
    __builtin_amdgcn_s_setprio(0);
    __builtin_amdgcn_s_barrier();

    // ---- phase 2: read A m4-7 (4); stage B(kt+2) -> cur-B (free since p1 barrier)
#pragma unroll
    for (int m = 0; m < 4; ++m) afr[m] = *(const i32x4*)(smA + (4 + m) * 1024);
    if (kt + 2 < NT) { stageB(cur, kt + 2, 0); stageB(cur, kt + 2, 1); }
    __builtin_amdgcn_s_barrier();
    asm volatile("s_waitcnt lgkmcnt(0)" ::: "memory");
    __builtin_amdgcn_s_setprio(1);
#pragma unroll
    for (int m = 0; m < 4; ++m)
#pragma unroll
      for (int n = 0; n < 4; ++n)
        acc[4 + m][n] = __builtin_amdgcn_mfma_i32_16x16x64_i8(afr[m], bfr[n],
                                                              acc[4 + m][n], 0, 0, 0);
    __builtin_amdgcn_s_setprio(0);
    // counted vmcnt: queue = {B(kt+1):2, A(kt+1):2, B(kt+2):2}; drain thru A(kt+1)
    if (kt + 2 < NT) {
      asm volatile("s_waitcnt vmcnt(2)" ::: "memory");
    } else {
      asm volatile("s_waitcnt vmcnt(0)" ::: "memory");
    }
    __builtin_amdgcn_s_barrier();
  }

  // ---- epilogue: C/D col=lane&15, row=(lane>>4)*4+i ; out = acc*sx[r]*sc + bias
  const int orow0 = row0 + wr * 128 + ((l >> 4) << 2);
  const int ocol0 = col0 + wc * 64 + (l & 15);
#pragma unroll
  for (int n = 0; n < 4; ++n) {
    const int col = ocol0 + n * 16;
    const float sc = scale[col];
    const float bi = bias[col];
#pragma unroll
    for (int m = 0; m < 8; ++m) {
      const int r = orow0 + m * 16;
      const float4 sxv = *(const float4*)(sx + r);
      out[(size_t)(r + 0) * N_O + col] = (float)acc[m][n][0] * (sxv.x * sc) + bi;
      out[(size_t)(r + 1) * N_O + col] = (float)acc[m][n][1] * (sxv.y * sc) + bi;
      out[(size_t)(r + 2) * N_O + col] = (float)acc[m][n][2] * (sxv.z * sc) + bi;
      out[(size_t)(r + 3) * N_O + col] = (float)acc[m][n][3] * (sxv.w * sc) + bi;
    }
  }
}

extern "C" void kernel_launch(void* const* d_in, const int* in_sizes, int n_in,
                              void* d_out, int out_size, void* d_ws, size_t ws_size,
                              hipStream_t stream) {
  const float* x    = (const float*)d_in[0];
  const int*   q8   = (const int*)d_in[1];
  const float* s8   = (const float*)d_in[2];
  const int*   q4   = (const int*)d_in[3];
  const float* s4   = (const float*)d_in[4];
  const int*   inv  = (const int*)d_in[5];
  const float* bias = (const float*)d_in[6];
  float* out = (float*)d_out;

  // ws layout: Wq (16 MiB) | scale (16 KiB) | sx (64 KiB) | xq (64 MiB)
  char* ws = (char*)d_ws;
  char*  Wq    = ws;
  float* scale = (float*)(ws + (size_t)N_O * K_IN);
  float* sx    = (float*)(ws + (size_t)N_O * K_IN + 65536);
  char*  xq    = ws + (size_t)N_O * K_IN + 65536 + 65536;

  prep_kernel<<<N_O + M_TOK, 256, 0, stream>>>(x, (const int4*)q8, s8,
                                               (const int4*)q4, s4, inv,
                                               Wq, scale, sx, xq);
  gemm_i8<<<(M_TOK / 256) * (N_O / 256), 512, 0, stream>>>(xq, Wq, sx, scale,
                                                           bias, out);
}

// Round 5
// 382.508 us; speedup vs baseline: 1.4956x; 1.0167x over previous
//
#include <hip/hip_runtime.h>

// out[b,s,j] = sum_k x[b,s,k] * w_concat[inv_perm[j], k] + bias[j]
// INT8 path: weights exact in i8; x per-token quantized (sx = absmax/127).
// One i8 MFMA GEMM (mfma_i32_16x16x64_i8), i32 accum exact, epilogue
// out = acc * sx[row]*scale[col] + bias[col].
// Round 4: 4-cluster K-tile with one-phase read-ahead + counted lgkmcnt(2)
// (never full-drain before MFMA), 2 barriers/K-tile, counted vmcnt(2).

#define M_TOK 16384
#define N_O   4096
#define K_IN  4096
#define N8F   2048
#define NT    (K_IN / 64)   // 64 K-tiles of BK=64 bytes

typedef __attribute__((ext_vector_type(4))) int   i32x4;

__device__ __forceinline__ void gl_lds16(const void* g, void* l) {
  __builtin_amdgcn_global_load_lds(
      (const __attribute__((address_space(1))) unsigned int*)g,
      (__attribute__((address_space(3))) unsigned int*)l, 16, 0, 0);
}

__device__ __forceinline__ int clampq(float f) {
  int q = (int)rintf(f);
  return q > 127 ? 127 : (q < -127 ? -127 : q);
}

// ---- fused prep: blocks [0,N_O) pack weights to i8; blocks [N_O, N_O+M_TOK)
// ---- quantize one token each (absmax -> sx, xq).
__global__ void prep_kernel(const float* __restrict__ x,
                            const int4* __restrict__ q8, const float* __restrict__ s8,
                            const int4* __restrict__ q4, const float* __restrict__ s4,
                            const int* __restrict__ inv,
                            char* __restrict__ Wq, float* __restrict__ scale,
                            float* __restrict__ sx, char* __restrict__ xq) {
  __shared__ float red[4];
  const int t = threadIdx.x;
  if (blockIdx.x < N_O) {
    const int j = blockIdx.x;
    const int c = inv[j];
    const int4* src; float s;
    if (c < N8F) { src = q8 + (size_t)c * (K_IN / 4);         s = s8[c]; }
    else         { src = q4 + (size_t)(c - N8F) * (K_IN / 4); s = s4[c - N8F]; }
    if (t == 0) scale[j] = s;
    unsigned dw[4];
#pragma unroll
    for (int i = 0; i < 4; ++i) {
      int4 v = src[t * 4 + i];
      dw[i] = (v.x & 255) | ((v.y & 255) << 8) | ((v.z & 255) << 16)
            | ((unsigned)(v.w & 255) << 24);
    }
    *(uint4*)(Wq + (size_t)j * K_IN + t * 16) = make_uint4(dw[0], dw[1], dw[2], dw[3]);
  } else {
    const int T = blockIdx.x - N_O;
    const float4* xr = (const float4*)(x + (size_t)T * K_IN);
    float4 v[4];
    float m = 0.f;
#pragma unroll
    for (int i = 0; i < 4; ++i) {
      v[i] = xr[t * 4 + i];
      m = fmaxf(m, fmaxf(fmaxf(fabsf(v[i].x), fabsf(v[i].y)),
                         fmaxf(fabsf(v[i].z), fabsf(v[i].w))));
    }
#pragma unroll
    for (int o = 32; o; o >>= 1) m = fmaxf(m, __shfl_xor(m, o));
    if ((t & 63) == 0) red[t >> 6] = m;
    __syncthreads();
    m = fmaxf(fmaxf(red[0], red[1]), fmaxf(red[2], red[3]));
    const float rq = m > 0.f ? 127.f / m : 0.f;
    if (t == 0) sx[T] = m * (1.f / 127.f);
    unsigned dw[4];
#pragma unroll
    for (int i = 0; i < 4; ++i) {
      int a0 = clampq(v[i].x * rq), a1 = clampq(v[i].y * rq);
      int a2 = clampq(v[i].z * rq), a3 = clampq(v[i].w * rq);
      dw[i] = (a0 & 255) | ((a1 & 255) << 8) | ((a2 & 255) << 16)
            | ((unsigned)(a3 & 255) << 24);
    }
    *(uint4*)(xq + (size_t)T * K_IN + t * 16) = make_uint4(dw[0], dw[1], dw[2], dw[3]);
  }
}

// ================= 256x256 i8 GEMM, BK=64, 4-cluster read-ahead schedule ==========
// LDS (64 KiB): buf*32768 + { A: h*8192 | B: 16384 + h*8192 }
// half = 128 rows x 64 i8 (64B rows); swizzle: phys_chunk = chunk ^ ((row>>1)&3)
#define MFMA2(MB, X0, X1)                                                              \
  acc[(MB)][0]     = __builtin_amdgcn_mfma_i32_16x16x64_i8(X0, b0v, acc[(MB)][0], 0, 0, 0); \
  acc[(MB)][1]     = __builtin_amdgcn_mfma_i32_16x16x64_i8(X0, b1v, acc[(MB)][1], 0, 0, 0); \
  acc[(MB)][2]     = __builtin_amdgcn_mfma_i32_16x16x64_i8(X0, b2v, acc[(MB)][2], 0, 0, 0); \
  acc[(MB)][3]     = __builtin_amdgcn_mfma_i32_16x16x64_i8(X0, b3v, acc[(MB)][3], 0, 0, 0); \
  acc[(MB) + 1][0] = __builtin_amdgcn_mfma_i32_16x16x64_i8(X1, b0v, acc[(MB) + 1][0], 0, 0, 0); \
  acc[(MB) + 1][1] = __builtin_amdgcn_mfma_i32_16x16x64_i8(X1, b1v, acc[(MB) + 1][1], 0, 0, 0); \
  acc[(MB) + 1][2] = __builtin_amdgcn_mfma_i32_16x16x64_i8(X1, b2v, acc[(MB) + 1][2], 0, 0, 0); \
  acc[(MB) + 1][3] = __builtin_amdgcn_mfma_i32_16x16x64_i8(X1, b3v, acc[(MB) + 1][3], 0, 0, 0);

// One K-tile, CUR = compile-time buffer parity.
// Entering state: b0v..b3v,aU0,aU1 hold tile kt's frags; those 6 ds_reads in flight.
#define KT_BODY(CUR, kt)                                                               \
  {                                                                                    \
    const char* smA = sm + (CUR) * 32768 + aOff;                                       \
    const char* nA  = sm + (((CUR) ^ 1)) * 32768 + aOff;                               \
    const char* nB  = sm + (((CUR) ^ 1)) * 32768 + bOff;                               \
    /* ---- P0: stage A(kt+1)->buf^1; read aV=a2,a3; MFMA m0,m1 */                     \
    if ((kt) + 1 < NT) { stageA((CUR) ^ 1, (kt) + 1, 0); stageA((CUR) ^ 1, (kt) + 1, 1); } \
    aV0 = *(const i32x4*)(smA + 2 * 1024);                                             \
    aV1 = *(const i32x4*)(smA + 3 * 1024);                                             \
    asm volatile("s_waitcnt lgkmcnt(2)" ::: "memory");                                 \
    __builtin_amdgcn_sched_barrier(0);                                                 \
    __builtin_amdgcn_s_setprio(1);                                                     \
    MFMA2(0, aU0, aU1);                                                                \
    __builtin_amdgcn_s_setprio(0);                                                     \
    /* ---- P1: read aU=a4,a5; barrier; stage B(kt+2)->cur-B; MFMA m2,m3 */            \
    aU0 = *(const i32x4*)(smA + 4 * 1024);                                             \
    aU1 = *(const i32x4*)(smA + 5 * 1024);                                             \
    __builtin_amdgcn_s_barrier();                                                      \
    __builtin_amdgcn_sched_barrier(0);                                                 \
    if ((kt) + 2 < NT) { stageB((CUR), (kt) + 2, 0); stageB((CUR), (kt) + 2, 1); }     \
    asm volatile("s_waitcnt lgkmcnt(2)" ::: "memory");                                 \
    __builtin_amdgcn_sched_barrier(0);                                                 \
    __builtin_amdgcn_s_setprio(1);                                                     \
    MFMA2(2, aV0, aV1);                                                                \
    __builtin_amdgcn_s_setprio(0);                                                     \
    /* ---- P2: read aV=a6,a7; MFMA m4,m5 */                                           \
    aV0 = *(const i32x4*)(smA + 6 * 1024);                                             \
    aV1 = *(const i32x4*)(smA + 7 * 1024);                                             \
    asm volatile("s_waitcnt lgkmcnt(2)" ::: "memory");                                 \
    __builtin_amdgcn_sched_barrier(0);                                                 \
    __builtin_amdgcn_s_setprio(1);                                                     \
    MFMA2(4, aU0, aU1);                                                                \
    __builtin_amdgcn_s_setprio(0);                                                     \
    /* ---- P3: counted vmcnt; drain last 2 reads; barrier; MFMA m6,m7; next reads */  \
    if ((kt) + 2 < NT) { asm volatile("s_waitcnt vmcnt(2)" ::: "memory"); }            \
    else               { asm volatile("s_waitcnt vmcnt(0)" ::: "memory"); }            \
    asm volatile("s_waitcnt lgkmcnt(0)" ::: "memory");                                 \
    __builtin_amdgcn_sched_barrier(0);                                                 \
    __builtin_amdgcn_s_barrier();                                                      \
    __builtin_amdgcn_sched_barrier(0);                                                 \
    __builtin_amdgcn_s_setprio(1);                                                     \
    MFMA2(6, aV0, aV1);                                                                \
    __builtin_amdgcn_s_setprio(0);                                                     \
    if ((kt) + 1 < NT) {                                                               \
      b0v = *(const i32x4*)(nB + 0 * 1024);                                            \
      b1v = *(const i32x4*)(nB + 1 * 1024);                                            \
      b2v = *(const i32x4*)(nB + 2 * 1024);                                            \
      b3v = *(const i32x4*)(nB + 3 * 1024);                                            \
      aU0 = *(const i32x4*)(nA + 0 * 1024);                                            \
      aU1 = *(const i32x4*)(nA + 1 * 1024);                                            \
    }                                                                                  \
  }

__global__ __launch_bounds__(512, 2)
void gemm_i8(const char* __restrict__ xq, const char* __restrict__ Wq,
             const float* __restrict__ sx, const float* __restrict__ scale,
             const float* __restrict__ bias, float* __restrict__ out) {
  __shared__ __align__(16) char sm[65536];
  const int t = threadIdx.x;
  const int w = t >> 6, l = t & 63;
  const int wr = w >> 2, wc = w & 3;            // 2M x 4N waves, 128x64 each
  const int bm = blockIdx.x >> 4, bn = blockIdx.x & 15;
  const int row0 = bm * 256, col0 = bn * 256;

  // staging: wave w covers rows w*16..w*16+15 of each 128-row half; lane l ->
  // row-in-slice l>>2, phys chunk l&3; global source chunk inverse-swizzled.
  const int srow = l >> 2;
  const int schunk = ((l & 3) ^ ((l >> 3) & 3)) * 16;
  const char* aG = xq + (size_t)(row0 + w * 16 + srow) * K_IN + schunk;
  const char* bG = Wq + (size_t)(col0 + w * 16 + srow) * K_IN + schunk;
  char* aL0 = sm + w * 1024;
  char* bL0 = sm + 16384 + w * 1024;

  auto stageA = [&](int buf, int kt, int h) {
    gl_lds16(aG + (size_t)h * (128 * K_IN) + kt * 64, aL0 + buf * 32768 + h * 8192);
  };
  auto stageB = [&](int buf, int kt, int h) {
    gl_lds16(bG + (size_t)h * (128 * K_IN) + kt * 64, bL0 + buf * 32768 + h * 8192);
  };

  // fragment read: row_local = frag*16 + (l&15), k-chunk = l>>4, swizzled
  const int fRoff = (l & 15) * 64 + ((((l >> 4) ^ ((l >> 1) & 3))) << 4);
  const int aOff = wr * 8192 + fRoff;
  const int bOff = 16384 + (wc >> 1) * 8192 + (wc & 1) * 4096 + fRoff;

  i32x4 acc[8][4];
#pragma unroll
  for (int m = 0; m < 8; ++m)
#pragma unroll
    for (int n = 0; n < 4; ++n) acc[m][n] = (i32x4){0, 0, 0, 0};

  // prologue: tile0 {A,B} -> buf0, tile1 {B} -> buf1; drain thru tile0; entering reads
  stageA(0, 0, 0); stageA(0, 0, 1); stageB(0, 0, 0); stageB(0, 0, 1);
  stageB(1, 1, 0); stageB(1, 1, 1);
  asm volatile("s_waitcnt vmcnt(2)" ::: "memory");
  __builtin_amdgcn_s_barrier();
  __builtin_amdgcn_sched_barrier(0);

  i32x4 b0v, b1v, b2v, b3v, aU0, aU1, aV0, aV1;
  b0v = *(const i32x4*)(sm + bOff + 0 * 1024);
  b1v = *(const i32x4*)(sm + bOff + 1 * 1024);
  b2v = *(const i32x4*)(sm + bOff + 2 * 1024);
  b3v = *(const i32x4*)(sm + bOff + 3 * 1024);
  aU0 = *(const i32x4*)(sm + aOff + 0 * 1024);
  aU1 = *(const i32x4*)(sm + aOff + 1 * 1024);

  for (int kt = 0; kt < NT; kt += 2) {
    KT_BODY(0, kt);
    KT_BODY(1, kt + 1);
  }

  // ---- epilogue: C/D col=lane&15, row=(lane>>4)*4+i ; out = acc*sx[r]*sc + bias
  const int orow0 = row0 + wr * 128 + ((l >> 4) << 2);
  const int ocol0 = col0 + wc * 64 + (l & 15);
#pragma unroll
  for (int n = 0; n < 4; ++n) {
    const int col = ocol0 + n * 16;
    const float sc = scale[col];
    const float bi = bias[col];
#pragma unroll
    for (int m = 0; m < 8; ++m) {
      const int r = orow0 + m * 16;
      const float4 sxv = *(const float4*)(sx + r);
      out[(size_t)(r + 0) * N_O + col] = (float)acc[m][n][0] * (sxv.x * sc) + bi;
      out[(size_t)(r + 1) * N_O + col] = (float)acc[m][n][1] * (sxv.y * sc) + bi;
      out[(size_t)(r + 2) * N_O + col] = (float)acc[m][n][2] * (sxv.z * sc) + bi;
      out[(size_t)(r + 3) * N_O + col] = (float)acc[m][n][3] * (sxv.w * sc) + bi;
    }
  }
}

extern "C" void kernel_launch(void* const* d_in, const int* in_sizes, int n_in,
                              void* d_out, int out_size, void* d_ws, size_t ws_size,
                              hipStream_t stream) {
  const float* x    = (const float*)d_in[0];
  const int*   q8   = (const int*)d_in[1];
  const float* s8   = (const float*)d_in[2];
  const int*   q4   = (const int*)d_in[3];
  const float* s4   = (const float*)d_in[4];
  const int*   inv  = (const int*)d_in[5];
  const float* bias = (const float*)d_in[6];
  float* out = (float*)d_out;

  // ws layout: Wq (16 MiB) | scale (16 KiB) | sx (64 KiB) | xq (64 MiB)
  char* ws = (char*)d_ws;
  char*  Wq    = ws;
  float* scale = (float*)(ws + (size_t)N_O * K_IN);
  float* sx    = (float*)(ws + (size_t)N_O * K_IN + 65536);
  char*  xq    = ws + (size_t)N_O * K_IN + 65536 + 65536;

  prep_kernel<<<N_O + M_TOK, 256, 0, stream>>>(x, (const int4*)q8, s8,
                                               (const int4*)q4, s4, inv,
                                               Wq, scale, sx, xq);
  gemm_i8<<<(M_TOK / 256) * (N_O / 256), 512, 0, stream>>>(xq, Wq, sx, scale,
                                                           bias, out);
}